// Round 1
// baseline (64.157 us; speedup 1.0000x reference)
//
#include <hip/hip_runtime.h>

#define EPS_CONST 1e-8f

// log(sigmoid(x) + 1e-8), safe across the full fp32 range:
//  x << 0: __expf(-x) -> inf, 1/(1+inf)=0, log(1e-8) = -18.42 (matches ref)
//  x >> 0: __expf(-x) -> 0,  log(1+1e-8) ~ 0
__device__ __forceinline__ float logsig_eps(float x) {
    float s = 1.0f / (1.0f + __expf(-x));
    return __logf(s + EPS_CONST);
}

// ---------------- kernel 1: c[n][s] = mu[n] + exp(log_sigma[n]) * eps[s][n]
// stored transposed (N, S) so each node's S samples are contiguous (32 B for S=8)
__global__ void compute_c_s8(const float* __restrict__ mu,
                             const float* __restrict__ ls,
                             const float* __restrict__ eps,
                             float* __restrict__ c, int N) {
    int n = blockIdx.x * blockDim.x + threadIdx.x;
    if (n >= N) return;
    float m  = mu[n];
    float sg = __expf(ls[n]);
    float v[8];
#pragma unroll
    for (int s = 0; s < 8; ++s) v[s] = m + sg * eps[(size_t)s * N + n];
    float4* dst = (float4*)(c + (size_t)n * 8);
    dst[0] = make_float4(v[0], v[1], v[2], v[3]);
    dst[1] = make_float4(v[4], v[5], v[6], v[7]);
}

__global__ void compute_c_gen(const float* __restrict__ mu,
                              const float* __restrict__ ls,
                              const float* __restrict__ eps,
                              float* __restrict__ c, int N, int S) {
    int n = blockIdx.x * blockDim.x + threadIdx.x;
    if (n >= N) return;
    float m  = mu[n];
    float sg = __expf(ls[n]);
    for (int s = 0; s < S; ++s) c[(size_t)n * S + s] = m + sg * eps[(size_t)s * N + n];
}

// ---------------- dtype detection: int64 edges have zero high words (values < 1e5)
__global__ void detect_i64(const unsigned int* __restrict__ raw, int* __restrict__ flag) {
    if (blockIdx.x == 0 && threadIdx.x == 0) {
        int is64 = 1;
        for (int k = 0; k < 256; ++k) {
            if (raw[2 * k + 1] != 0u) { is64 = 0; break; }
        }
        *flag = is64;
    }
}

// ---------------- kernel 2: per-edge loglik, S=8 fast path
__global__ void edge_loglik_s8(const void* __restrict__ edges_raw,
                               const float* __restrict__ c,
                               const int* __restrict__ flag,
                               float* __restrict__ out,
                               long long E, float inv_s) {
    long long tid    = (long long)blockIdx.x * blockDim.x + threadIdx.x;
    long long stride = (long long)gridDim.x * blockDim.x;
    float acc = 0.0f;
    bool is64 = (*flag != 0);   // wave-uniform branch

    if (is64) {
        const longlong2* edges = (const longlong2*)edges_raw;
        for (long long e = tid; e < E; e += stride) {
            longlong2 ij = edges[e];
            const float4* ci = (const float4*)(c + (size_t)ij.x * 8);
            const float4* cj = (const float4*)(c + (size_t)ij.y * 8);
            float4 a0 = ci[0], a1 = ci[1];
            float4 b0 = cj[0], b1 = cj[1];
            acc += logsig_eps(a0.x * b0.x) + logsig_eps(a0.y * b0.y) +
                   logsig_eps(a0.z * b0.z) + logsig_eps(a0.w * b0.w) +
                   logsig_eps(a1.x * b1.x) + logsig_eps(a1.y * b1.y) +
                   logsig_eps(a1.z * b1.z) + logsig_eps(a1.w * b1.w);
        }
    } else {
        const int2* edges = (const int2*)edges_raw;
        for (long long e = tid; e < E; e += stride) {
            int2 ij = edges[e];
            const float4* ci = (const float4*)(c + (size_t)ij.x * 8);
            const float4* cj = (const float4*)(c + (size_t)ij.y * 8);
            float4 a0 = ci[0], a1 = ci[1];
            float4 b0 = cj[0], b1 = cj[1];
            acc += logsig_eps(a0.x * b0.x) + logsig_eps(a0.y * b0.y) +
                   logsig_eps(a0.z * b0.z) + logsig_eps(a0.w * b0.w) +
                   logsig_eps(a1.x * b1.x) + logsig_eps(a1.y * b1.y) +
                   logsig_eps(a1.z * b1.z) + logsig_eps(a1.w * b1.w);
        }
    }

    // wave (64-lane) reduction
#pragma unroll
    for (int off = 32; off > 0; off >>= 1) acc += __shfl_down(acc, off, 64);
    __shared__ float wsum[8];
    int lane = threadIdx.x & 63;
    int wid  = threadIdx.x >> 6;
    if (lane == 0) wsum[wid] = acc;
    __syncthreads();
    if (threadIdx.x == 0) {
        float s = 0.0f;
        int nw = blockDim.x >> 6;
        for (int w = 0; w < nw; ++w) s += wsum[w];
        atomicAdd(out, s * inv_s);
    }
}

// generic-S fallback (not expected to run; harness uses S=8)
__global__ void edge_loglik_gen(const void* __restrict__ edges_raw,
                                const float* __restrict__ c,
                                const int* __restrict__ flag,
                                float* __restrict__ out,
                                long long E, int S, float inv_s) {
    long long tid    = (long long)blockIdx.x * blockDim.x + threadIdx.x;
    long long stride = (long long)gridDim.x * blockDim.x;
    float acc = 0.0f;
    bool is64 = (*flag != 0);
    for (long long e = tid; e < E; e += stride) {
        long long i, j;
        if (is64) {
            const long long* ed = (const long long*)edges_raw;
            i = ed[2 * e]; j = ed[2 * e + 1];
        } else {
            const int* ed = (const int*)edges_raw;
            i = ed[2 * e]; j = ed[2 * e + 1];
        }
        for (int s = 0; s < S; ++s)
            acc += logsig_eps(c[(size_t)i * S + s] * c[(size_t)j * S + s]);
    }
#pragma unroll
    for (int off = 32; off > 0; off >>= 1) acc += __shfl_down(acc, off, 64);
    __shared__ float wsum[8];
    int lane = threadIdx.x & 63;
    int wid  = threadIdx.x >> 6;
    if (lane == 0) wsum[wid] = acc;
    __syncthreads();
    if (threadIdx.x == 0) {
        float s = 0.0f;
        int nw = blockDim.x >> 6;
        for (int w = 0; w < nw; ++w) s += wsum[w];
        atomicAdd(out, s * inv_s);
    }
}

extern "C" void kernel_launch(void* const* d_in, const int* in_sizes, int n_in,
                              void* d_out, int out_size, void* d_ws, size_t ws_size,
                              hipStream_t stream) {
    const float* mu    = (const float*)d_in[0];
    const float* ls    = (const float*)d_in[1];
    const float* eps   = (const float*)d_in[2];
    const void*  edges = d_in[3];

    int       N = in_sizes[0];
    int       S = in_sizes[2] / N;                 // 8
    long long E = (long long)in_sizes[3] / 2;      // 3.2M

    float* c    = (float*)d_ws;
    int*   flag = (int*)((char*)d_ws + (size_t)N * S * sizeof(float));
    float* out  = (float*)d_out;

    // d_out is poisoned 0xAA and not re-zeroed between replays
    hipMemsetAsync(d_out, 0, (size_t)out_size * sizeof(float), stream);

    detect_i64<<<1, 64, 0, stream>>>((const unsigned int*)edges, flag);

    int cblocks = (N + 255) / 256;
    if (S == 8) {
        compute_c_s8<<<cblocks, 256, 0, stream>>>(mu, ls, eps, c, N);
        edge_loglik_s8<<<2048, 256, 0, stream>>>(edges, c, flag, out, E, 1.0f / (float)S);
    } else {
        compute_c_gen<<<cblocks, 256, 0, stream>>>(mu, ls, eps, c, N, S);
        edge_loglik_gen<<<2048, 256, 0, stream>>>(edges, c, flag, out, E, S, 1.0f / (float)S);
    }
}

// Round 2
// 54.503 us; speedup vs baseline: 1.1771x; 1.1771x over previous
//
#include <hip/hip_runtime.h>
#include <hip/hip_fp16.h>

#define EPS_CONST 1e-8f

// log(sigmoid(x) + 1e-8) ~= -log(1 + min(exp(-x), 1e8))
// exp(-x) clamped at 1e8 makes -log(...) bottom out at log(1e-8) = -18.42,
// which implements the +eps floor exactly for x < -20 and x > -16; in the
// narrow band x in [-20,-16] the max per-term error is 0.69 (population
// ~0.3% of terms -> total error ~2e3, threshold 9.6e4). Saves the v_rcp.
__device__ __forceinline__ float logsig_eps(float x) {
    float t = fminf(__expf(-x), 1.0e8f);
    return -__logf(1.0f + t);
}

// ---------------- kernel 1: c[n][s] = mu[n] + exp(log_sigma[n]) * eps[s][n]
// stored fp16, transposed (N, S): node's 8 samples = 16 B = one uint4 gather
__global__ void compute_c_h8(const float* __restrict__ mu,
                             const float* __restrict__ ls,
                             const float* __restrict__ eps,
                             __half2* __restrict__ c, int N) {
    int n = blockIdx.x * blockDim.x + threadIdx.x;
    if (n >= N) return;
    float m  = mu[n];
    float sg = __expf(ls[n]);
    float v[8];
#pragma unroll
    for (int s = 0; s < 8; ++s) v[s] = m + sg * eps[(size_t)s * N + n];
    __half2* dst = c + (size_t)n * 4;
#pragma unroll
    for (int s = 0; s < 4; ++s) dst[s] = __floats2half2_rn(v[2 * s], v[2 * s + 1]);
}

__global__ void compute_c_gen(const float* __restrict__ mu,
                              const float* __restrict__ ls,
                              const float* __restrict__ eps,
                              __half* __restrict__ c, int N, int S) {
    int n = blockIdx.x * blockDim.x + threadIdx.x;
    if (n >= N) return;
    float m  = mu[n];
    float sg = __expf(ls[n]);
    for (int s = 0; s < S; ++s) c[(size_t)n * S + s] = __float2half(m + sg * eps[(size_t)s * N + n]);
}

// ---------------- dtype detect (parallel, 64 lanes) + zero d_out (fused)
__global__ void detect_and_zero(const unsigned int* __restrict__ raw,
                                int* __restrict__ flag,
                                float* __restrict__ out, int out_size) {
    int lane = threadIdx.x;
    // int64 edges (values < 1e5) have all-zero high words; int32 edges don't
    unsigned int acc = 0;
#pragma unroll
    for (int k = 0; k < 4; ++k) acc |= raw[2 * (lane * 4 + k) + 1];
#pragma unroll
    for (int off = 32; off > 0; off >>= 1) acc |= __shfl_down(acc, off, 64);
    if (lane == 0) *flag = (acc == 0u) ? 1 : 0;
    for (int i = lane; i < out_size; i += 64) out[i] = 0.0f;
}

__device__ __forceinline__ float terms8(uint4 A, uint4 B) {
    const __half2* ah = (const __half2*)&A;
    const __half2* bh = (const __half2*)&B;
    float acc = 0.0f;
#pragma unroll
    for (int k = 0; k < 4; ++k) {
        float2 a = __half22float2(ah[k]);
        float2 b = __half22float2(bh[k]);
        acc += logsig_eps(a.x * b.x) + logsig_eps(a.y * b.y);
    }
    return acc;
}

// ---------------- kernel 2: per-edge loglik, S=8 / int32 fast path
// processes 2 edges per iteration: one int4 edge load + 4 uint4 gathers
__global__ void edge_loglik_s8(const void* __restrict__ edges_raw,
                               const uint4* __restrict__ c,
                               const int* __restrict__ flag,
                               float* __restrict__ out,
                               long long E, float inv_s) {
    long long tid    = (long long)blockIdx.x * blockDim.x + threadIdx.x;
    long long stride = (long long)gridDim.x * blockDim.x;
    float acc = 0.0f;
    bool is64 = (*flag != 0);   // wave-uniform branch

    if (!is64) {
        const int4* ep = (const int4*)edges_raw;   // 2 edges per int4
        long long P = E >> 1;
        for (long long p = tid; p < P; p += stride) {
            int4 ee = ep[p];
            uint4 a = c[ee.x];
            uint4 b = c[ee.y];
            uint4 d = c[ee.z];
            uint4 f = c[ee.w];
            acc += terms8(a, b) + terms8(d, f);
        }
        if ((E & 1) && tid == 0) {
            const int2* el = (const int2*)edges_raw;
            int2 ij = el[E - 1];
            acc += terms8(c[ij.x], c[ij.y]);
        }
    } else {
        const longlong2* ep = (const longlong2*)edges_raw;
        for (long long e = tid; e < E; e += stride) {
            longlong2 ij = ep[e];
            acc += terms8(c[ij.x], c[ij.y]);
        }
    }

    // wave (64-lane) reduction
#pragma unroll
    for (int off = 32; off > 0; off >>= 1) acc += __shfl_down(acc, off, 64);
    __shared__ float wsum[8];
    int lane = threadIdx.x & 63;
    int wid  = threadIdx.x >> 6;
    if (lane == 0) wsum[wid] = acc;
    __syncthreads();
    if (threadIdx.x == 0) {
        float s = 0.0f;
        int nw = blockDim.x >> 6;
        for (int w = 0; w < nw; ++w) s += wsum[w];
        atomicAdd(out, s * inv_s);
    }
}

// generic-S fallback (not expected to run; harness uses S=8)
__global__ void edge_loglik_gen(const void* __restrict__ edges_raw,
                                const __half* __restrict__ c,
                                const int* __restrict__ flag,
                                float* __restrict__ out,
                                long long E, int S, float inv_s) {
    long long tid    = (long long)blockIdx.x * blockDim.x + threadIdx.x;
    long long stride = (long long)gridDim.x * blockDim.x;
    float acc = 0.0f;
    bool is64 = (*flag != 0);
    for (long long e = tid; e < E; e += stride) {
        long long i, j;
        if (is64) {
            const long long* ed = (const long long*)edges_raw;
            i = ed[2 * e]; j = ed[2 * e + 1];
        } else {
            const int* ed = (const int*)edges_raw;
            i = ed[2 * e]; j = ed[2 * e + 1];
        }
        for (int s = 0; s < S; ++s)
            acc += logsig_eps(__half2float(c[i * S + s]) * __half2float(c[j * S + s]));
    }
#pragma unroll
    for (int off = 32; off > 0; off >>= 1) acc += __shfl_down(acc, off, 64);
    __shared__ float wsum[8];
    int lane = threadIdx.x & 63;
    int wid  = threadIdx.x >> 6;
    if (lane == 0) wsum[wid] = acc;
    __syncthreads();
    if (threadIdx.x == 0) {
        float s = 0.0f;
        int nw = blockDim.x >> 6;
        for (int w = 0; w < nw; ++w) s += wsum[w];
        atomicAdd(out, s * inv_s);
    }
}

extern "C" void kernel_launch(void* const* d_in, const int* in_sizes, int n_in,
                              void* d_out, int out_size, void* d_ws, size_t ws_size,
                              hipStream_t stream) {
    const float* mu    = (const float*)d_in[0];
    const float* ls    = (const float*)d_in[1];
    const float* eps   = (const float*)d_in[2];
    const void*  edges = d_in[3];

    int       N = in_sizes[0];
    int       S = in_sizes[2] / N;                 // 8
    long long E = (long long)in_sizes[3] / 2;      // 3.2M

    __half* c   = (__half*)d_ws;
    int*   flag = (int*)((char*)d_ws + (size_t)N * S * sizeof(__half) + 256);
    float* out  = (float*)d_out;

    detect_and_zero<<<1, 64, 0, stream>>>((const unsigned int*)edges, flag, out, out_size);

    int cblocks = (N + 255) / 256;
    if (S == 8) {
        compute_c_h8<<<cblocks, 256, 0, stream>>>(mu, ls, eps, (__half2*)c, N);
        edge_loglik_s8<<<2048, 256, 0, stream>>>(edges, (const uint4*)c, flag, out, E, 1.0f / (float)S);
    } else {
        compute_c_gen<<<cblocks, 256, 0, stream>>>(mu, ls, eps, c, N, S);
        edge_loglik_gen<<<2048, 256, 0, stream>>>(edges, c, flag, out, E, S, 1.0f / (float)S);
    }
}

// Round 3
// 48.059 us; speedup vs baseline: 1.3350x; 1.1341x over previous
//
#include <hip/hip_runtime.h>
#include <hip/hip_fp16.h>

// term = log(sigmoid(x) + 1e-8) ~= -log(1 + min(exp(-x), 1e8))
// The 1e8 clamp implements the +1e-8 floor: -log(1+1e8) = log(1e-8) = -18.42.
// Exact for x < -20 and x > -16; in x in [-20,-16] max per-term err 0.69,
// population ~0.3% -> total ~2e3 << 9.6e4 threshold.
//
// 4-way log pairing: sum_k log(1+t_k) = log(prod_k (1+t_k)); prod <= (1+1e8)^4
// = 1e32 < fp32 max. Cuts logs 4x.

// ---------------- kernel 1: c[n][s] = mu[n] + exp(log_sigma[n]) * eps[s][n]
// fp16, transposed (N,S): node's 8 samples = 16 B = one uint4 gather.
// Last block additionally: edge-dtype detect + zero d_out.
__global__ void compute_c_h8(const float* __restrict__ mu,
                             const float* __restrict__ ls,
                             const float* __restrict__ eps,
                             __half2* __restrict__ c, int N,
                             const unsigned int* __restrict__ raw_edges,
                             int* __restrict__ flag,
                             float* __restrict__ out, int out_size) {
    if (blockIdx.x == gridDim.x - 1) {
        // detect: int64 edges (values < 1e5) have all-zero high words
        int lane = threadIdx.x;
        if (lane < 64) {
            unsigned int acc = 0;
#pragma unroll
            for (int k = 0; k < 4; ++k) acc |= raw_edges[2 * (lane * 4 + k) + 1];
#pragma unroll
            for (int off = 32; off > 0; off >>= 1) acc |= __shfl_down(acc, off, 64);
            if (lane == 0) *flag = (acc == 0u) ? 1 : 0;
        }
        for (int i = threadIdx.x; i < out_size; i += blockDim.x) out[i] = 0.0f;
        return;
    }
    int n = blockIdx.x * blockDim.x + threadIdx.x;
    if (n >= N) return;
    float m  = mu[n];
    float sg = __expf(ls[n]);
    float v[8];
#pragma unroll
    for (int s = 0; s < 8; ++s) v[s] = m + sg * eps[(size_t)s * N + n];
    __half2* dst = c + (size_t)n * 4;
#pragma unroll
    for (int s = 0; s < 4; ++s) dst[s] = __floats2half2_rn(v[2 * s], v[2 * s + 1]);
}

__global__ void compute_c_gen(const float* __restrict__ mu,
                              const float* __restrict__ ls,
                              const float* __restrict__ eps,
                              __half* __restrict__ c, int N, int S,
                              const unsigned int* __restrict__ raw_edges,
                              int* __restrict__ flag,
                              float* __restrict__ out, int out_size) {
    if (blockIdx.x == gridDim.x - 1) {
        int lane = threadIdx.x;
        if (lane < 64) {
            unsigned int acc = 0;
#pragma unroll
            for (int k = 0; k < 4; ++k) acc |= raw_edges[2 * (lane * 4 + k) + 1];
#pragma unroll
            for (int off = 32; off > 0; off >>= 1) acc |= __shfl_down(acc, off, 64);
            if (lane == 0) *flag = (acc == 0u) ? 1 : 0;
        }
        for (int i = threadIdx.x; i < out_size; i += blockDim.x) out[i] = 0.0f;
        return;
    }
    int n = blockIdx.x * blockDim.x + threadIdx.x;
    if (n >= N) return;
    float m  = mu[n];
    float sg = __expf(ls[n]);
    for (int s = 0; s < S; ++s) c[(size_t)n * S + s] = __float2half(m + sg * eps[(size_t)s * N + n]);
}

// sum over 8 samples of log(1 + min(exp(-ci*cj), 1e8)), via 2 logs of 4-way products
__device__ __forceinline__ float edge_term(uint4 A, uint4 B) {
    const __half2* ah = (const __half2*)&A;
    const __half2* bh = (const __half2*)&B;
    float t[8];
#pragma unroll
    for (int k = 0; k < 4; ++k) {
        __half2 xh = __hmul2(ah[k], bh[k]);      // packed product (sat -> inf ok)
        float2 xf = __half22float2(xh);
        t[2 * k]     = fminf(__expf(-xf.x), 1.0e8f);
        t[2 * k + 1] = fminf(__expf(-xf.y), 1.0e8f);
    }
    float p0 = 1.0f + t[0];
    p0 = __builtin_fmaf(p0, t[1], p0);
    p0 = __builtin_fmaf(p0, t[2], p0);
    p0 = __builtin_fmaf(p0, t[3], p0);
    float p1 = 1.0f + t[4];
    p1 = __builtin_fmaf(p1, t[5], p1);
    p1 = __builtin_fmaf(p1, t[6], p1);
    p1 = __builtin_fmaf(p1, t[7], p1);
    return __logf(p0) + __logf(p1);              // positive; negated at the end
}

// ---------------- kernel 2: per-edge loglik, S=8 / int32 fast path
// 4 edges (2 independent int4 edge loads + 8 independent gathers) per iteration
__global__ void __launch_bounds__(256, 8)
edge_loglik_s8(const void* __restrict__ edges_raw,
               const uint4* __restrict__ c,
               const int* __restrict__ flag,
               float* __restrict__ out,
               long long E, float inv_s) {
    long long tid    = (long long)blockIdx.x * blockDim.x + threadIdx.x;
    long long stride = (long long)gridDim.x * blockDim.x;
    float acc = 0.0f;
    bool is64 = (*flag != 0);   // wave-uniform branch

    if (!is64) {
        const int4* ep = (const int4*)edges_raw;   // 2 edges per int4
        long long P = E >> 1;
        for (long long q = tid; q < P; q += 2 * stride) {
            long long q1 = q + stride;
            bool has1 = q1 < P;
            int4 e0 = ep[q];
            int4 e1 = has1 ? ep[q1] : e0;
            // 8 independent gathers in flight
            uint4 a0 = c[e0.x], b0 = c[e0.y], d0 = c[e0.z], f0 = c[e0.w];
            uint4 a1 = c[e1.x], b1 = c[e1.y], d1 = c[e1.z], f1 = c[e1.w];
            float s = edge_term(a0, b0) + edge_term(d0, f0);
            if (has1) s += edge_term(a1, b1) + edge_term(d1, f1);
            acc += s;
        }
        if ((E & 1) && tid == 0) {
            const int2* el = (const int2*)edges_raw;
            int2 ij = el[E - 1];
            acc += edge_term(c[ij.x], c[ij.y]);
        }
    } else {
        const longlong2* ep = (const longlong2*)edges_raw;
        for (long long e = tid; e < E; e += stride) {
            longlong2 ij = ep[e];
            acc += edge_term(c[ij.x], c[ij.y]);
        }
    }

    // wave (64-lane) reduction
#pragma unroll
    for (int off = 32; off > 0; off >>= 1) acc += __shfl_down(acc, off, 64);
    __shared__ float wsum[8];
    int lane = threadIdx.x & 63;
    int wid  = threadIdx.x >> 6;
    if (lane == 0) wsum[wid] = acc;
    __syncthreads();
    if (threadIdx.x == 0) {
        float s = 0.0f;
        int nw = blockDim.x >> 6;
        for (int w = 0; w < nw; ++w) s += wsum[w];
        atomicAdd(out, -s * inv_s);
    }
}

// generic-S fallback (not expected to run; harness uses S=8)
__global__ void edge_loglik_gen(const void* __restrict__ edges_raw,
                                const __half* __restrict__ c,
                                const int* __restrict__ flag,
                                float* __restrict__ out,
                                long long E, int S, float inv_s) {
    long long tid    = (long long)blockIdx.x * blockDim.x + threadIdx.x;
    long long stride = (long long)gridDim.x * blockDim.x;
    float acc = 0.0f;
    bool is64 = (*flag != 0);
    for (long long e = tid; e < E; e += stride) {
        long long i, j;
        if (is64) {
            const long long* ed = (const long long*)edges_raw;
            i = ed[2 * e]; j = ed[2 * e + 1];
        } else {
            const int* ed = (const int*)edges_raw;
            i = ed[2 * e]; j = ed[2 * e + 1];
        }
        for (int s = 0; s < S; ++s) {
            float x = __half2float(c[i * S + s]) * __half2float(c[j * S + s]);
            acc += __logf(1.0f + fminf(__expf(-x), 1.0e8f));
        }
    }
#pragma unroll
    for (int off = 32; off > 0; off >>= 1) acc += __shfl_down(acc, off, 64);
    __shared__ float wsum[8];
    int lane = threadIdx.x & 63;
    int wid  = threadIdx.x >> 6;
    if (lane == 0) wsum[wid] = acc;
    __syncthreads();
    if (threadIdx.x == 0) {
        float s = 0.0f;
        int nw = blockDim.x >> 6;
        for (int w = 0; w < nw; ++w) s += wsum[w];
        atomicAdd(out, -s * inv_s);
    }
}

extern "C" void kernel_launch(void* const* d_in, const int* in_sizes, int n_in,
                              void* d_out, int out_size, void* d_ws, size_t ws_size,
                              hipStream_t stream) {
    const float* mu    = (const float*)d_in[0];
    const float* ls    = (const float*)d_in[1];
    const float* eps   = (const float*)d_in[2];
    const void*  edges = d_in[3];

    int       N = in_sizes[0];
    int       S = in_sizes[2] / N;                 // 8
    long long E = (long long)in_sizes[3] / 2;      // 3.2M

    __half* c   = (__half*)d_ws;
    int*   flag = (int*)((char*)d_ws + (size_t)N * S * sizeof(__half) + 256);
    float* out  = (float*)d_out;

    int cblocks = (N + 255) / 256 + 1;             // +1 block: detect + zero d_out
    if (S == 8) {
        compute_c_h8<<<cblocks, 256, 0, stream>>>(mu, ls, eps, (__half2*)c, N,
                                                  (const unsigned int*)edges, flag, out, out_size);
        edge_loglik_s8<<<2048, 256, 0, stream>>>(edges, (const uint4*)c, flag, out, E, 1.0f / (float)S);
    } else {
        compute_c_gen<<<cblocks, 256, 0, stream>>>(mu, ls, eps, c, N, S,
                                                   (const unsigned int*)edges, flag, out, out_size);
        edge_loglik_gen<<<2048, 256, 0, stream>>>(edges, c, flag, out, E, S, 1.0f / (float)S);
    }
}